// Round 2
// baseline (4050.890 us; speedup 1.0000x reference)
//
#include <hip/hip_runtime.h>
#include <hip/hip_bf16.h>
#include <stdint.h>

#define DEVINL __device__ __forceinline__

typedef __attribute__((ext_vector_type(8))) short short8;
typedef __attribute__((ext_vector_type(4))) float float4v;

// Problem constants: V=50000, T=32, E=256, HID=512, H=256, L=512, B=64
// Token count M = L*B = 32768. Gates 4H = 1024 per direction, N = 2048 combined.

DEVINL float bf2f(short s) {
  union { unsigned u; float f; } v; v.u = ((unsigned)(unsigned short)s) << 16; return v.f;
}
DEVINL unsigned short f2bf(float f) {
  union { float f; unsigned u; } v; v.f = f;
  unsigned r = v.u + 0x7FFFu + ((v.u >> 16) & 1u);  // RNE
  return (unsigned short)(r >> 16);
}
DEVINL float sigmf(float x) { return __fdividef(1.0f, 1.0f + __expf(-x)); }
DEVINL float tanhf_(float x) {
  x = fminf(20.0f, fmaxf(-20.0f, x));
  float e = __expf(-2.0f * x);
  return __fdividef(1.0f - e, 1.0f + e);
}

// ---------------- K0: f32 -> bf16 converts (8 elems / thread / iter) ----------------
__global__ void k_cvt(const float* __restrict__ src, short* __restrict__ dst, int n8) {
  int i = blockIdx.x * blockDim.x + threadIdx.x;
  int stride = gridDim.x * blockDim.x;
  for (; i < n8; i += stride) {
    const float4v* s = (const float4v*)(src + (size_t)i * 8);
    float4v a = s[0], b = s[1];
    short8 o;
    o[0] = (short)f2bf(a[0]); o[1] = (short)f2bf(a[1]);
    o[2] = (short)f2bf(a[2]); o[3] = (short)f2bf(a[3]);
    o[4] = (short)f2bf(b[0]); o[5] = (short)f2bf(b[1]);
    o[6] = (short)f2bf(b[2]); o[7] = (short)f2bf(b[3]);
    ((short8*)dst)[i] = o;
  }
}

__global__ void k_bias(const float* __restrict__ a1, const float* __restrict__ a2,
                       const float* __restrict__ b1, const float* __restrict__ b2,
                       float* __restrict__ o) {
  int i = blockIdx.x * blockDim.x + threadIdx.x;  // 0..2047
  o[i] = (i < 1024) ? (a1[i] + a2[i]) : (b1[i - 1024] + b2[i - 1024]);
}

// ---------------- K1: x_proj = gather(emb)·W_ihᵀ + (b_ih+b_hh), bf16 out ----------------
// Tiles: 128 tokens × 128 gate-rows, K=256 fully LDS-resident, XOR-swizzled.
__launch_bounds__(256)
__global__ void k_xproj(const int* __restrict__ seqs, const short* __restrict__ embT,
                        const short* __restrict__ wihX, const float* __restrict__ biasX,
                        short* __restrict__ xproj) {
  __shared__ short As[128 * 256];
  __shared__ short Bs[128 * 256];
  __shared__ int ids[128];
  const int bm = blockIdx.x >> 4, bn = blockIdx.x & 15;
  const int tid = threadIdx.x;
  if (tid < 128) ids[tid] = seqs[bm * 128 + tid];
  __syncthreads();
#pragma unroll
  for (int i = 0; i < 16; ++i) {  // stage A (gathered embeddings)
    int task = tid + i * 256, row = task >> 5, kc = task & 31;
    short8 v = *(const short8*)(embT + (size_t)ids[row] * 256 + kc * 8);
    *(short8*)((char*)As + row * 512 + ((kc * 16) ^ ((row & 7) << 4))) = v;
  }
#pragma unroll
  for (int i = 0; i < 16; ++i) {  // stage B (W_ih rows)
    int task = tid + i * 256, row = task >> 5, kc = task & 31;
    short8 v = *(const short8*)(wihX + (size_t)(bn * 128 + row) * 256 + kc * 8);
    *(short8*)((char*)Bs + row * 512 + ((kc * 16) ^ ((row & 7) << 4))) = v;
  }
  __syncthreads();
  const int wave = tid >> 6, lane = tid & 63, l15 = lane & 15, l4 = lane >> 4;
  float4v acc[2][8];
#pragma unroll
  for (int m = 0; m < 2; ++m)
#pragma unroll
    for (int n = 0; n < 8; ++n) acc[m][n] = (float4v){0.f, 0.f, 0.f, 0.f};
#pragma unroll
  for (int kt = 0; kt < 8; ++kt) {
    const int kb = kt * 64 + l4 * 16;
    short8 a[2], b[8];
#pragma unroll
    for (int m = 0; m < 2; ++m) {
      int row = (wave * 2 + m) * 16 + l15;
      a[m] = *(short8*)((char*)As + row * 512 + (kb ^ ((row & 7) << 4)));
    }
#pragma unroll
    for (int n = 0; n < 8; ++n) {
      int row = n * 16 + l15;
      b[n] = *(short8*)((char*)Bs + row * 512 + (kb ^ ((row & 7) << 4)));
    }
#pragma unroll
    for (int m = 0; m < 2; ++m)
#pragma unroll
      for (int n = 0; n < 8; ++n)
        acc[m][n] = __builtin_amdgcn_mfma_f32_16x16x32_bf16(a[m], b[n], acc[m][n], 0, 0, 0);
  }
#pragma unroll
  for (int n = 0; n < 8; ++n) {
    int col = bn * 128 + n * 16 + l15;
    float bias = biasX[col];
#pragma unroll
    for (int m = 0; m < 2; ++m) {
      int token = bm * 128 + (wave * 2 + m) * 16 + l4 * 4;
#pragma unroll
      for (int q = 0; q < 4; ++q)
        xproj[(size_t)(token + q) * 2048 + col] = (short)f2bf(acc[m][n][q] + bias);
    }
  }
}

// ---------------- K2: bidirectional LSTM recurrence ----------------
// 32 WGs in 8 groups of 4: gid = bid&7 -> (dir, batch-quarter of 16); role rg = bid>>3
// owns hidden units [rg*64, rg*64+64). W_hh fragments stationary in VGPRs (128/lane).
// h exchanged via agent-scope 8B atomics in MALL-coherent hbuf[group][parity][beta][K].
// Sync: per-WAVE release flag stores (no RMW, no __syncthreads in the loop).
__launch_bounds__(256, 1)
__global__ void k_lstm(const short* __restrict__ xproj, const short* __restrict__ whhX,
                       const int* __restrict__ masks, short* __restrict__ h_all,
                       unsigned long long* __restrict__ hX, int* __restrict__ flags) {
  const int bid = blockIdx.x;
  const int gid = bid & 7;    // group: (dir, bq)
  const int rg  = bid >> 3;   // role: unit-slice 0..3
  const int dir = gid & 1, bq = gid >> 1;
  const int tid = threadIdx.x, w = tid >> 6, lane = tid & 63;
  const int l15 = lane & 15, l4 = lane >> 4;
  const int beta = l15;                      // batch within quarter
  const int bglob = bq * 16 + beta;          // global batch
  const int u0 = rg * 64 + w * 16 + l4 * 4;  // first of this thread's 4 hidden units

  // stationary W_hh A-fragments [gate][kt]: rows = units (l15), k = kt*32 + l4*8
  short8 wf[4][8];
#pragma unroll
  for (int g = 0; g < 4; ++g) {
    const short* wrow = whhX + (size_t)(dir * 1024 + g * 256 + rg * 64 + w * 16 + l15) * 256;
#pragma unroll
    for (int kt = 0; kt < 8; ++kt) wf[g][kt] = *(const short8*)(wrow + kt * 32 + l4 * 8);
  }

  unsigned long long* hbg = hX + (size_t)gid * 2048;  // 2 parity x 16 beta x 64 ull
  int* flg = flags + gid * 16;
  const int myflag = rg * 4 + w;

  float c[4] = {0.f, 0.f, 0.f, 0.f}, hq[4] = {0.f, 0.f, 0.f, 0.f};

  int tseq = dir ? 511 : 0;
  const short* xbase = xproj + dir * 1024 + rg * 64 + w * 16 + l4 * 4;
  unsigned long long xp[4];
#pragma unroll
  for (int g = 0; g < 4; ++g)
    xp[g] = *(const unsigned long long*)(xbase + (size_t)(tseq * 64 + bglob) * 2048 + g * 256);
  int mcur = masks[tseq * 64 + bglob];

#pragma unroll 1
  for (int step = 0; step < 512; ++step) {
    tseq = dir ? (511 - step) : step;
    float4v acc[4];
#pragma unroll
    for (int g = 0; g < 4; ++g) {
      float4v a;
#pragma unroll
      for (int q = 0; q < 4; ++q) a[q] = bf2f((short)(unsigned short)(xp[g] >> (16 * q)));
      acc[g] = a;
    }
    // prefetch next step's x_proj + mask: issued BEFORE the spin so HBM/L3
    // latency hides under the flag wait.
    int tn = dir ? (510 - step) : (step + 1);
    tn = tn < 0 ? 0 : (tn > 511 ? 511 : tn);
    unsigned long long xpn[4];
#pragma unroll
    for (int g = 0; g < 4; ++g)
      xpn[g] = *(const unsigned long long*)(xbase + (size_t)(tn * 64 + bglob) * 2048 + g * 256);
    int mn = masks[tn * 64 + bglob];

    if (step > 0) {
      // wait for all 16 producer waves of this group to have published h(step-1)
      int ready;
      do {
        ready = 1;
#pragma unroll
        for (int i = 0; i < 16; ++i)
          ready &= (__hip_atomic_load(&flg[i], __ATOMIC_RELAXED, __HIP_MEMORY_SCOPE_AGENT) >= step) ? 1 : 0;
      } while (!ready);
      __atomic_signal_fence(__ATOMIC_ACQUIRE);
      const unsigned long long* src = hbg + ((step - 1) & 1) * 1024 + beta * 64;
      unsigned long long bl[8][2];
#pragma unroll
      for (int kt = 0; kt < 8; ++kt) {
        bl[kt][0] = __hip_atomic_load(src + kt * 8 + l4 * 2,     __ATOMIC_RELAXED, __HIP_MEMORY_SCOPE_AGENT);
        bl[kt][1] = __hip_atomic_load(src + kt * 8 + l4 * 2 + 1, __ATOMIC_RELAXED, __HIP_MEMORY_SCOPE_AGENT);
      }
#pragma unroll
      for (int kt = 0; kt < 8; ++kt) {
        union { unsigned long long u[2]; short8 v; } uu;
        uu.u[0] = bl[kt][0]; uu.u[1] = bl[kt][1];
#pragma unroll
        for (int g = 0; g < 4; ++g)
          acc[g] = __builtin_amdgcn_mfma_f32_16x16x32_bf16(wf[g][kt], uu.v, acc[g], 0, 0, 0);
      }
    }

    float outq[4];
#pragma unroll
    for (int q = 0; q < 4; ++q) {
      float iv = sigmf(acc[0][q]);
      float fv = sigmf(acc[1][q]);
      float gv = tanhf_(acc[2][q]);
      float ov = sigmf(acc[3][q]);
      float cn = fv * c[q] + iv * gv;
      float hn = ov * tanhf_(cn);
      c[q]  = mcur ? cn : c[q];
      hq[q] = mcur ? hn : hq[q];
      outq[q] = mcur ? hn : 0.f;
    }
    unsigned long long hp =
        (unsigned long long)f2bf(hq[0]) | ((unsigned long long)f2bf(hq[1]) << 16) |
        ((unsigned long long)f2bf(hq[2]) << 32) | ((unsigned long long)f2bf(hq[3]) << 48);
    unsigned long long op =
        (unsigned long long)f2bf(outq[0]) | ((unsigned long long)f2bf(outq[1]) << 16) |
        ((unsigned long long)f2bf(outq[2]) << 32) | ((unsigned long long)f2bf(outq[3]) << 48);
    // publish h slice (this thread's 4 contiguous units for its batch row)
    __hip_atomic_store(hbg + (step & 1) * 1024 + beta * 64 + (u0 >> 2), hp,
                       __ATOMIC_RELAXED, __HIP_MEMORY_SCOPE_AGENT);
    // release: vmcnt(0) drains this wave's h store (and long-done prefetch), then signal
    __hip_atomic_store(&flg[myflag], step + 1, __ATOMIC_RELEASE, __HIP_MEMORY_SCOPE_AGENT);
    // h_all output store AFTER the signal — off the inter-WG critical path
    *(unsigned long long*)(h_all + (size_t)(tseq * 64 + bglob) * 512 + dir * 256 + u0) = op;
#pragma unroll
    for (int g = 0; g < 4; ++g) xp[g] = xpn[g];
    mcur = mn;
  }
}

// ---------------- K3: emissions = h_all·W_outᵀ + b_out (f32) ----------------
__launch_bounds__(256)
__global__ void k_emis(const short* __restrict__ h_all, const short* __restrict__ woutX,
                       const float* __restrict__ bout, float* __restrict__ emis) {
  const int tid = threadIdx.x, wave = tid >> 6, lane = tid & 63;
  const int l15 = lane & 15, l4 = lane >> 4;
  const int token0 = blockIdx.x * 256 + wave * 64;
  float4v acc[4][2];
#pragma unroll
  for (int m = 0; m < 4; ++m)
#pragma unroll
    for (int n = 0; n < 2; ++n) acc[m][n] = (float4v){0.f, 0.f, 0.f, 0.f};
#pragma unroll
  for (int kt = 0; kt < 16; ++kt) {
    short8 b[2];
#pragma unroll
    for (int n = 0; n < 2; ++n)
      b[n] = *(const short8*)(woutX + (size_t)(n * 16 + l15) * 512 + kt * 32 + l4 * 8);
#pragma unroll
    for (int m = 0; m < 4; ++m) {
      short8 a = *(const short8*)(h_all + (size_t)(token0 + m * 16 + l15) * 512 + kt * 32 + l4 * 8);
#pragma unroll
      for (int n = 0; n < 2; ++n)
        acc[m][n] = __builtin_amdgcn_mfma_f32_16x16x32_bf16(a, b[n], acc[m][n], 0, 0, 0);
    }
  }
#pragma unroll
  for (int n = 0; n < 2; ++n) {
    float bias = bout[n * 16 + l15];
#pragma unroll
    for (int m = 0; m < 4; ++m) {
      int token = token0 + m * 16 + l4 * 4;
#pragma unroll
      for (int q = 0; q < 4; ++q)
        emis[(size_t)(token + q) * 32 + n * 16 + l15] = acc[m][n][q] + bias;
    }
  }
}

// ---------------- K4: CRF numerator + partition scan + final reduce ----------------
__launch_bounds__(64)
__global__ void k_crf(const float* __restrict__ emis, const int* __restrict__ tags,
                      const int* __restrict__ masks, const float* __restrict__ strans,
                      const float* __restrict__ etrans, const float* __restrict__ trans,
                      float* __restrict__ out) {
  __shared__ float trans_s[1024];
  __shared__ float score_s[32];
  const int b = blockIdx.x, lane = threadIdx.x;
  for (int i = lane; i < 1024; i += 64) trans_s[i] = trans[i];

  // numerator (t-parallel across the wave)
  float num = 0.f; int lensum = 0;
#pragma unroll 1
  for (int i = 0; i < 8; ++i) {
    int t = lane + i * 64;
    int tg = tags[t * 64 + b];
    int m = masks[t * 64 + b];
    lensum += m;
    float e = emis[(size_t)(t * 64 + b) * 32 + tg];
    if (t == 0) num += strans[tg] + e;
    else if (m) num += e + trans[tags[(t - 1) * 64 + b] * 32 + tg];
  }
#pragma unroll
  for (int o = 32; o > 0; o >>= 1) { num += __shfl_down(num, o); lensum += __shfl_down(lensum, o); }
  num = __shfl(num, 0);
  lensum = __shfl(lensum, 0);
  num += etrans[tags[(lensum - 1) * 64 + b]];
  __syncthreads();

  const int jp = lane & 31, half = lane >> 5;
  if (lane < 32) score_s[jp] = strans[jp] + emis[(size_t)b * 32 + jp];
  __syncthreads();

  float e_next = emis[(size_t)(64 + b) * 32 + jp];
#pragma unroll 1
  for (int t = 1; t < 512; ++t) {
    float e = e_next;
    if (t < 511) e_next = emis[(size_t)((t + 1) * 64 + b) * 32 + jp];
    int m = masks[t * 64 + b];
    float v[16], mx = -1e30f;
#pragma unroll
    for (int j = 0; j < 16; ++j) {
      v[j] = score_s[half * 16 + j] + trans_s[(half * 16 + j) * 32 + jp];
      mx = fmaxf(mx, v[j]);
    }
    float sum = 0.f;
#pragma unroll
    for (int j = 0; j < 16; ++j) sum += __expf(v[j] - mx);
    float mo = __shfl_xor(mx, 32), so = __shfl_xor(sum, 32);
    float mn2 = fmaxf(mx, mo);
    sum = sum * __expf(mx - mn2) + so * __expf(mo - mn2);
    float nxt = e + mn2 + __logf(sum);
    float cur = score_s[jp];
    float ns = m ? nxt : cur;
    __syncthreads();
    if (lane < 32) score_s[jp] = ns;
    __syncthreads();
  }

  float vv = (lane < 32) ? (score_s[jp] + etrans[jp]) : -1e30f;
  float mx = vv;
#pragma unroll
  for (int o = 32; o > 0; o >>= 1) mx = fmaxf(mx, __shfl_xor(mx, o));
  float sm = (lane < 32) ? __expf(vv - mx) : 0.f;
#pragma unroll
  for (int o = 32; o > 0; o >>= 1) sm += __shfl_xor(sm, o);
  float lz = mx + __logf(sm);
  if (lane == 0) atomicAdd(out, -(num - lz) * (1.0f / 64.0f));
}

// ---------------- launch ----------------
extern "C" void kernel_launch(void* const* d_in, const int* in_sizes, int n_in,
                              void* d_out, int out_size, void* d_ws, size_t ws_size,
                              hipStream_t stream) {
  const int*   seqs  = (const int*)d_in[0];
  const int*   tags  = (const int*)d_in[1];
  const int*   masks = (const int*)d_in[2];
  const float* embed = (const float*)d_in[3];
  const float* Wihf  = (const float*)d_in[4];
  const float* Whhf  = (const float*)d_in[5];
  const float* bihf  = (const float*)d_in[6];
  const float* bhhf  = (const float*)d_in[7];
  const float* Wihb  = (const float*)d_in[8];
  const float* Whhb  = (const float*)d_in[9];
  const float* bihb  = (const float*)d_in[10];
  const float* bhhb  = (const float*)d_in[11];
  const float* Wout  = (const float*)d_in[12];
  const float* bout  = (const float*)d_in[13];
  const float* strn  = (const float*)d_in[14];
  const float* etrn  = (const float*)d_in[15];
  const float* trn   = (const float*)d_in[16];
  float* outf = (float*)d_out;

  char* ws = (char*)d_ws;
  short* xproj = (short*)(ws + 0);             // 134,217,728 B
  short* h_all = (short*)(ws + 134217728);     //  33,554,432 B
  float* emis  = (float*)(ws + 167772160);     //   4,194,304 B
  short* embT  = (short*)(ws + 171966464);     //  25,600,000 B
  short* wihX  = (short*)(ws + 197566464);     //   1,048,576 B
  short* whhX  = (short*)(ws + 198615040);     //   1,048,576 B
  short* woutX = (short*)(ws + 199663616);     //      32,768 B
  float* biasX = (float*)(ws + 199696384);     //       8,192 B
  unsigned long long* hX = (unsigned long long*)(ws + 199704576);  // 131,072 B (8 groups x 16 KiB)
  int* flags = (int*)(ws + 199835648);         //       8,192 B (8 groups x 16 ints used)

  hipMemsetAsync(flags, 0, 8192, stream);
  hipMemsetAsync(d_out, 0, 4, stream);

  k_cvt<<<2048, 256, 0, stream>>>(embed, embT, 1600000);
  k_cvt<<<128, 256, 0, stream>>>(Wihf, wihX, 32768);
  k_cvt<<<128, 256, 0, stream>>>(Wihb, wihX + 262144, 32768);
  k_cvt<<<128, 256, 0, stream>>>(Whhf, whhX, 32768);
  k_cvt<<<128, 256, 0, stream>>>(Whhb, whhX + 262144, 32768);
  k_cvt<<<8, 256, 0, stream>>>(Wout, woutX, 2048);
  k_bias<<<2, 1024, 0, stream>>>(bihf, bhhf, bihb, bhhb, biasX);
  k_xproj<<<4096, 256, 0, stream>>>(seqs, embT, wihX, biasX, xproj);
  k_lstm<<<32, 256, 0, stream>>>(xproj, whhX, masks, h_all, hX, flags);
  k_emis<<<128, 256, 0, stream>>>(h_all, woutX, bout, emis);
  k_crf<<<64, 64, 0, stream>>>(emis, tags, masks, strn, etrn, trn, outf);
}

// Round 3
// 3131.962 us; speedup vs baseline: 1.2934x; 1.2934x over previous
//
#include <hip/hip_runtime.h>
#include <hip/hip_bf16.h>
#include <stdint.h>

#define DEVINL __device__ __forceinline__

typedef __attribute__((ext_vector_type(8))) short short8;
typedef __attribute__((ext_vector_type(4))) float float4v;
typedef __attribute__((ext_vector_type(4))) int int4v;

// Problem constants: V=50000, T=32, E=256, HID=512, H=256, L=512, B=64

DEVINL float bf2f(short s) {
  union { unsigned u; float f; } v; v.u = ((unsigned)(unsigned short)s) << 16; return v.f;
}
DEVINL unsigned short f2bf(float f) {
  union { float f; unsigned u; } v; v.f = f;
  unsigned r = v.u + 0x7FFFu + ((v.u >> 16) & 1u);  // RNE
  return (unsigned short)(r >> 16);
}
DEVINL float sigmf(float x) { return __fdividef(1.0f, 1.0f + __expf(-x)); }
DEVINL float tanhf_(float x) {
  x = fminf(20.0f, fmaxf(-20.0f, x));
  float e = __expf(-2.0f * x);
  return __fdividef(1.0f - e, 1.0f + e);
}

// lgkm-only workgroup barrier: does NOT drain vmcnt (keeps global prefetches in flight)
#define LBAR() do { \
  asm volatile("s_waitcnt lgkmcnt(0)" ::: "memory"); \
  __builtin_amdgcn_sched_barrier(0); \
  __builtin_amdgcn_s_barrier(); \
  __builtin_amdgcn_sched_barrier(0); \
} while (0)

// ---------------- K0: f32 -> bf16 converts ----------------
__global__ void k_cvt(const float* __restrict__ src, short* __restrict__ dst, int n8) {
  int i = blockIdx.x * blockDim.x + threadIdx.x;
  int stride = gridDim.x * blockDim.x;
  for (; i < n8; i += stride) {
    const float4v* s = (const float4v*)(src + (size_t)i * 8);
    float4v a = s[0], b = s[1];
    short8 o;
    o[0] = (short)f2bf(a[0]); o[1] = (short)f2bf(a[1]);
    o[2] = (short)f2bf(a[2]); o[3] = (short)f2bf(a[3]);
    o[4] = (short)f2bf(b[0]); o[5] = (short)f2bf(b[1]);
    o[6] = (short)f2bf(b[2]); o[7] = (short)f2bf(b[3]);
    ((short8*)dst)[i] = o;
  }
}

__global__ void k_bias(const float* __restrict__ a1, const float* __restrict__ a2,
                       const float* __restrict__ b1, const float* __restrict__ b2,
                       float* __restrict__ o) {
  int i = blockIdx.x * blockDim.x + threadIdx.x;  // 0..2047
  o[i] = (i < 1024) ? (a1[i] + a2[i]) : (b1[i - 1024] + b2[i - 1024]);
}

// ---------------- K-wmax: per-direction max|W_hh| ----------------
__global__ void k_wmax(const float* __restrict__ Wf, const float* __restrict__ Wb,
                       unsigned* __restrict__ wmax) {
  int i = blockIdx.x * blockDim.x + threadIdx.x;
  int stride = gridDim.x * blockDim.x;
  unsigned mf = 0, mb = 0;
  for (int k = i; k < 262144; k += stride) {
    mf = max(mf, __float_as_uint(fabsf(Wf[k])));
    mb = max(mb, __float_as_uint(fabsf(Wb[k])));
  }
#pragma unroll
  for (int o = 32; o > 0; o >>= 1) {
    mf = max(mf, (unsigned)__shfl_down((int)mf, o));
    mb = max(mb, (unsigned)__shfl_down((int)mb, o));
  }
  if ((threadIdx.x & 63) == 0) { atomicMax(wmax + 0, mf); atomicMax(wmax + 1, mb); }
}

// ---------------- K-wquant: W_hh f32 -> int8 MFMA fragments ----------------
// Layout: whhQ[((((dir*4+g)*4+w)*4+m)*4+kt)*1024 + lane*16 + j]
//   unit = w*64 + m*16 + (lane&15); k = kt*64 + (lane>>4)*16 + j
__global__ void k_wquant(const float* __restrict__ Wf, const float* __restrict__ Wb,
                         const float* __restrict__ wmax, char* __restrict__ whhQ) {
  int idx = blockIdx.x * blockDim.x + threadIdx.x;  // 0..131071 (quad of k)
  int dir = idx >> 16;
  int rem = idx & 65535;
  int r = rem >> 6;          // 0..1023 = g*256+unit
  int k = (rem & 63) * 4;
  const float* W = dir ? Wb : Wf;
  float s = 127.0f / fmaxf(wmax[dir], 1e-20f);
  int g = r >> 8, unit = r & 255;
  int w = unit >> 6, m = (unit >> 4) & 3, row = unit & 15;
  int kt = k >> 6, l4 = (k >> 4) & 3, j = k & 15;
  int lane = l4 * 16 + row;
  unsigned out = 0;
#pragma unroll
  for (int t = 0; t < 4; ++t) {
    float v = W[(size_t)r * 256 + k + t] * s;
    int q = (int)rintf(v);
    q = q < -127 ? -127 : (q > 127 ? 127 : q);
    out |= ((unsigned)(q & 255)) << (8 * t);
  }
  *(unsigned*)(whhQ + (size_t)dir * 262144 + g * 65536 + w * 16384 + m * 4096 + kt * 1024 + lane * 16 + j) = out;
}

// ---------------- K1: x_proj = gather(emb)·W_ihᵀ + (b_ih+b_hh), bf16 out ----------------
__launch_bounds__(256)
__global__ void k_xproj(const int* __restrict__ seqs, const short* __restrict__ embT,
                        const short* __restrict__ wihX, const float* __restrict__ biasX,
                        short* __restrict__ xproj) {
  __shared__ short As[128 * 256];
  __shared__ short Bs[128 * 256];
  __shared__ int ids[128];
  const int bm = blockIdx.x >> 4, bn = blockIdx.x & 15;
  const int tid = threadIdx.x;
  if (tid < 128) ids[tid] = seqs[bm * 128 + tid];
  __syncthreads();
#pragma unroll
  for (int i = 0; i < 16; ++i) {
    int task = tid + i * 256, row = task >> 5, kc = task & 31;
    short8 v = *(const short8*)(embT + (size_t)ids[row] * 256 + kc * 8);
    *(short8*)((char*)As + row * 512 + ((kc * 16) ^ ((row & 7) << 4))) = v;
  }
#pragma unroll
  for (int i = 0; i < 16; ++i) {
    int task = tid + i * 256, row = task >> 5, kc = task & 31;
    short8 v = *(const short8*)(wihX + (size_t)(bn * 128 + row) * 256 + kc * 8);
    *(short8*)((char*)Bs + row * 512 + ((kc * 16) ^ ((row & 7) << 4))) = v;
  }
  __syncthreads();
  const int wave = tid >> 6, lane = tid & 63, l15 = lane & 15, l4 = lane >> 4;
  float4v acc[2][8];
#pragma unroll
  for (int m = 0; m < 2; ++m)
#pragma unroll
    for (int n = 0; n < 8; ++n) acc[m][n] = (float4v){0.f, 0.f, 0.f, 0.f};
#pragma unroll
  for (int kt = 0; kt < 8; ++kt) {
    const int kb = kt * 64 + l4 * 16;
    short8 a[2], b[8];
#pragma unroll
    for (int m = 0; m < 2; ++m) {
      int row = (wave * 2 + m) * 16 + l15;
      a[m] = *(short8*)((char*)As + row * 512 + (kb ^ ((row & 7) << 4)));
    }
#pragma unroll
    for (int n = 0; n < 8; ++n) {
      int row = n * 16 + l15;
      b[n] = *(short8*)((char*)Bs + row * 512 + (kb ^ ((row & 7) << 4)));
    }
#pragma unroll
    for (int m = 0; m < 2; ++m)
#pragma unroll
      for (int n = 0; n < 8; ++n)
        acc[m][n] = __builtin_amdgcn_mfma_f32_16x16x32_bf16(a[m], b[n], acc[m][n], 0, 0, 0);
  }
#pragma unroll
  for (int n = 0; n < 8; ++n) {
    int col = bn * 128 + n * 16 + l15;
    float bias = biasX[col];
#pragma unroll
    for (int m = 0; m < 2; ++m) {
      int token = bm * 128 + (wave * 2 + m) * 16 + l4 * 4;
#pragma unroll
      for (int q = 0; q < 4; ++q)
        xproj[(size_t)(token + q) * 2048 + col] = (short)f2bf(acc[m][n][q] + bias);
    }
  }
}

// ---------------- K2: bidirectional LSTM recurrence, fully WG-local ----------------
// 8 WGs = dir (bid&1) x batch-quarter (bid>>1). 256 threads, 4 waves.
// Wave w owns units [w*64, w*64+64). ALL W_hh int8 fragments in VGPRs (256/lane).
// h (int8, XOR-swizzled) exchanged via 4KB LDS; two lgkm-only barriers per step.
// No atomics, no flags, no cross-WG traffic.
__launch_bounds__(256, 1)
__global__ void k_lstm(const short* __restrict__ xproj, const char* __restrict__ whhQ,
                       const float* __restrict__ wmax, const int* __restrict__ masks,
                       short* __restrict__ h_all) {
  __shared__ char lds_h[16 * 256];  // [beta][unit(swizzled)] int8
  const int bid = blockIdx.x;
  const int dir = bid & 1, bq = bid >> 1;
  const int tid = threadIdx.x, w = tid >> 6, lane = tid & 63;
  const int beta = lane & 15, l4 = lane >> 4;
  const int bglob = bq * 16 + beta;
  const float factor = wmax[dir] * (1.0f / 16129.0f);  // (wm/127) * (1/127)

  // stationary int8 W_hh fragments [gate][mtile][kt]
  int4v wf[4][4][4];
  {
    const char* base = whhQ + (size_t)dir * 262144 + w * 16384 + lane * 16;
#pragma unroll
    for (int g = 0; g < 4; ++g)
#pragma unroll
      for (int m = 0; m < 4; ++m)
#pragma unroll
        for (int kt = 0; kt < 4; ++kt)
          wf[g][m][kt] = *(const int4v*)(base + g * 65536 + m * 4096 + kt * 1024);
  }

  // swizzled LDS pointers
  const char* rd_ptr[4];
  char* wr_ptr[4];
#pragma unroll
  for (int kt = 0; kt < 4; ++kt)
    rd_ptr[kt] = lds_h + beta * 256 + ((kt * 64 + l4 * 16) ^ ((beta & 7) << 4));
#pragma unroll
  for (int m = 0; m < 4; ++m)
    wr_ptr[m] = lds_h + beta * 256 + ((w * 64 + m * 16 + l4 * 4) ^ ((beta & 7) << 4));

  // h(-1) = 0
  ((int4v*)lds_h)[tid] = (int4v){0, 0, 0, 0};
  __syncthreads();

  float c[4][4], hq[4][4];
#pragma unroll
  for (int m = 0; m < 4; ++m)
#pragma unroll
    for (int q = 0; q < 4; ++q) { c[m][q] = 0.f; hq[m][q] = 0.f; }

  int tseq = dir ? 511 : 0;
  const short* xb = xproj + dir * 1024 + w * 64 + l4 * 4;
  unsigned long long xp[4][4], xpn[4][4];
#pragma unroll
  for (int g = 0; g < 4; ++g)
#pragma unroll
    for (int m = 0; m < 4; ++m)
      xp[g][m] = *(const unsigned long long*)(xb + (size_t)(tseq * 64 + bglob) * 2048 + g * 256 + m * 16);
  int mcur = masks[tseq * 64 + bglob];

#pragma unroll 1
  for (int step = 0; step < 512; ++step) {
    tseq = dir ? (511 - step) : step;
    // B-fragments: h(t-1) int8, all 256 units for this thread's batch column
    int4v bfr[4];
#pragma unroll
    for (int kt = 0; kt < 4; ++kt) bfr[kt] = *(const int4v*)rd_ptr[kt];

    // prefetch next step's x_proj + mask (hides HBM under this step's compute)
    int tn = dir ? (510 - step) : (step + 1);
    tn = tn < 0 ? 0 : (tn > 511 ? 511 : tn);
#pragma unroll
    for (int g = 0; g < 4; ++g)
#pragma unroll
      for (int m = 0; m < 4; ++m)
        xpn[g][m] = *(const unsigned long long*)(xb + (size_t)(tn * 64 + bglob) * 2048 + g * 256 + m * 16);
    int mn = masks[tn * 64 + bglob];

    // all waves' reads complete before anyone overwrites lds_h
    LBAR();

    // recurrent GEMM: iacc[g][m] = sum_k W_int8 * h_int8
    int4v iacc[4][4];
#pragma unroll
    for (int g = 0; g < 4; ++g)
#pragma unroll
      for (int m = 0; m < 4; ++m) {
        int4v t = __builtin_amdgcn_mfma_i32_16x16x64_i8(wf[g][m][0], bfr[0], (int4v){0, 0, 0, 0}, 0, 0, 0);
        t = __builtin_amdgcn_mfma_i32_16x16x64_i8(wf[g][m][1], bfr[1], t, 0, 0, 0);
        t = __builtin_amdgcn_mfma_i32_16x16x64_i8(wf[g][m][2], bfr[2], t, 0, 0, 0);
        iacc[g][m] = __builtin_amdgcn_mfma_i32_16x16x64_i8(wf[g][m][3], bfr[3], t, 0, 0, 0);
      }

    size_t hoff = (size_t)(tseq * 64 + bglob) * 512 + dir * 256 + w * 64 + l4 * 4;
#pragma unroll
    for (int m = 0; m < 4; ++m) {
      unsigned qpack = 0;
      unsigned long long opack = 0ull;
#pragma unroll
      for (int q = 0; q < 4; ++q) {
        float pi = bf2f((short)(unsigned short)(xp[0][m] >> (16 * q))) + (float)iacc[0][m][q] * factor;
        float pf = bf2f((short)(unsigned short)(xp[1][m] >> (16 * q))) + (float)iacc[1][m][q] * factor;
        float pg = bf2f((short)(unsigned short)(xp[2][m] >> (16 * q))) + (float)iacc[2][m][q] * factor;
        float po = bf2f((short)(unsigned short)(xp[3][m] >> (16 * q))) + (float)iacc[3][m][q] * factor;
        float iv = sigmf(pi), fv = sigmf(pf), gv = tanhf_(pg), ov = sigmf(po);
        float cn = fv * c[m][q] + iv * gv;
        float hn = ov * tanhf_(cn);
        c[m][q] = mcur ? cn : c[m][q];
        float hqn = mcur ? hn : hq[m][q];
        hq[m][q] = hqn;
        float outv = mcur ? hn : 0.f;
        int qi = (int)rintf(hqn * 127.0f);
        qpack |= ((unsigned)(qi & 255)) << (8 * q);
        opack |= ((unsigned long long)f2bf(outv)) << (16 * q);
      }
      *(unsigned*)wr_ptr[m] = qpack;                                  // publish h int8 to LDS
      *(unsigned long long*)(h_all + hoff + m * 16) = opack;          // bf16 output (off critical path)
    }

    // writes visible before next step's reads
    LBAR();

#pragma unroll
    for (int g = 0; g < 4; ++g)
#pragma unroll
      for (int m = 0; m < 4; ++m) xp[g][m] = xpn[g][m];
    mcur = mn;
  }
}

// ---------------- K3: emissions = h_all·W_outᵀ + b_out (f32) ----------------
__launch_bounds__(256)
__global__ void k_emis(const short* __restrict__ h_all, const short* __restrict__ woutX,
                       const float* __restrict__ bout, float* __restrict__ emis) {
  const int tid = threadIdx.x, wave = tid >> 6, lane = tid & 63;
  const int l15 = lane & 15, l4 = lane >> 4;
  const int token0 = blockIdx.x * 256 + wave * 64;
  float4v acc[4][2];
#pragma unroll
  for (int m = 0; m < 4; ++m)
#pragma unroll
    for (int n = 0; n < 2; ++n) acc[m][n] = (float4v){0.f, 0.f, 0.f, 0.f};
#pragma unroll
  for (int kt = 0; kt < 16; ++kt) {
    short8 b[2];
#pragma unroll
    for (int n = 0; n < 2; ++n)
      b[n] = *(const short8*)(woutX + (size_t)(n * 16 + l15) * 512 + kt * 32 + l4 * 8);
#pragma unroll
    for (int m = 0; m < 4; ++m) {
      short8 a = *(const short8*)(h_all + (size_t)(token0 + m * 16 + l15) * 512 + kt * 32 + l4 * 8);
#pragma unroll
      for (int n = 0; n < 2; ++n)
        acc[m][n] = __builtin_amdgcn_mfma_f32_16x16x32_bf16(a, b[n], acc[m][n], 0, 0, 0);
    }
  }
#pragma unroll
  for (int n = 0; n < 2; ++n) {
    float bias = bout[n * 16 + l15];
#pragma unroll
    for (int m = 0; m < 4; ++m) {
      int token = token0 + m * 16 + l4 * 4;
#pragma unroll
      for (int q = 0; q < 4; ++q)
        emis[(size_t)(token + q) * 32 + n * 16 + l15] = acc[m][n][q] + bias;
    }
  }
}

// ---------------- K4: CRF numerator + partition scan + final reduce ----------------
__launch_bounds__(64)
__global__ void k_crf(const float* __restrict__ emis, const int* __restrict__ tags,
                      const int* __restrict__ masks, const float* __restrict__ strans,
                      const float* __restrict__ etrans, const float* __restrict__ trans,
                      float* __restrict__ out) {
  __shared__ float trans_s[1024];
  __shared__ float score_s[32];
  const int b = blockIdx.x, lane = threadIdx.x;
  for (int i = lane; i < 1024; i += 64) trans_s[i] = trans[i];

  float num = 0.f; int lensum = 0;
#pragma unroll 1
  for (int i = 0; i < 8; ++i) {
    int t = lane + i * 64;
    int tg = tags[t * 64 + b];
    int m = masks[t * 64 + b];
    lensum += m;
    float e = emis[(size_t)(t * 64 + b) * 32 + tg];
    if (t == 0) num += strans[tg] + e;
    else if (m) num += e + trans[tags[(t - 1) * 64 + b] * 32 + tg];
  }
#pragma unroll
  for (int o = 32; o > 0; o >>= 1) { num += __shfl_down(num, o); lensum += __shfl_down(lensum, o); }
  num = __shfl(num, 0);
  lensum = __shfl(lensum, 0);
  num += etrans[tags[(lensum - 1) * 64 + b]];
  __syncthreads();

  const int jp = lane & 31, half = lane >> 5;
  if (lane < 32) score_s[jp] = strans[jp] + emis[(size_t)b * 32 + jp];
  __syncthreads();

  float e_next = emis[(size_t)(64 + b) * 32 + jp];
#pragma unroll 1
  for (int t = 1; t < 512; ++t) {
    float e = e_next;
    if (t < 511) e_next = emis[(size_t)((t + 1) * 64 + b) * 32 + jp];
    int m = masks[t * 64 + b];
    float v[16], mx = -1e30f;
#pragma unroll
    for (int j = 0; j < 16; ++j) {
      v[j] = score_s[half * 16 + j] + trans_s[(half * 16 + j) * 32 + jp];
      mx = fmaxf(mx, v[j]);
    }
    float sum = 0.f;
#pragma unroll
    for (int j = 0; j < 16; ++j) sum += __expf(v[j] - mx);
    float mo = __shfl_xor(mx, 32), so = __shfl_xor(sum, 32);
    float mn2 = fmaxf(mx, mo);
    sum = sum * __expf(mx - mn2) + so * __expf(mo - mn2);
    float nxt = e + mn2 + __logf(sum);
    float cur = score_s[jp];
    float ns = m ? nxt : cur;
    __syncthreads();
    if (lane < 32) score_s[jp] = ns;
    __syncthreads();
  }

  float vv = (lane < 32) ? (score_s[jp] + etrans[jp]) : -1e30f;
  float mx = vv;
#pragma unroll
  for (int o = 32; o > 0; o >>= 1) mx = fmaxf(mx, __shfl_xor(mx, o));
  float sm = (lane < 32) ? __expf(vv - mx) : 0.f;
#pragma unroll
  for (int o = 32; o > 0; o >>= 1) sm += __shfl_xor(sm, o);
  float lz = mx + __logf(sm);
  if (lane == 0) atomicAdd(out, -(num - lz) * (1.0f / 64.0f));
}

// ---------------- launch ----------------
extern "C" void kernel_launch(void* const* d_in, const int* in_sizes, int n_in,
                              void* d_out, int out_size, void* d_ws, size_t ws_size,
                              hipStream_t stream) {
  const int*   seqs  = (const int*)d_in[0];
  const int*   tags  = (const int*)d_in[1];
  const int*   masks = (const int*)d_in[2];
  const float* embed = (const float*)d_in[3];
  const float* Wihf  = (const float*)d_in[4];
  const float* Whhf  = (const float*)d_in[5];
  const float* bihf  = (const float*)d_in[6];
  const float* bhhf  = (const float*)d_in[7];
  const float* Wihb  = (const float*)d_in[8];
  const float* Whhb  = (const float*)d_in[9];
  const float* bihb  = (const float*)d_in[10];
  const float* bhhb  = (const float*)d_in[11];
  const float* Wout  = (const float*)d_in[12];
  const float* bout  = (const float*)d_in[13];
  const float* strn  = (const float*)d_in[14];
  const float* etrn  = (const float*)d_in[15];
  const float* trn   = (const float*)d_in[16];
  float* outf = (float*)d_out;

  char* ws = (char*)d_ws;
  short* xproj = (short*)(ws + 0);             // 134,217,728 B
  short* h_all = (short*)(ws + 134217728);     //  33,554,432 B
  float* emis  = (float*)(ws + 167772160);     //   4,194,304 B
  short* embT  = (short*)(ws + 171966464);     //  25,600,000 B
  short* wihX  = (short*)(ws + 197566464);     //   1,048,576 B
  char*  whhQ  = (char*)(ws + 198615040);      //     524,288 B (int8 fragments)
  unsigned* wmaxb = (unsigned*)(ws + 199139328); //         8 B
  short* woutX = (short*)(ws + 199663616);     //      32,768 B
  float* biasX = (float*)(ws + 199696384);     //       8,192 B

  hipMemsetAsync(d_out, 0, 4, stream);
  hipMemsetAsync(wmaxb, 0, 8, stream);

  k_cvt<<<2048, 256, 0, stream>>>(embed, embT, 1600000);
  k_cvt<<<128, 256, 0, stream>>>(Wihf, wihX, 32768);
  k_cvt<<<128, 256, 0, stream>>>(Wihb, wihX + 262144, 32768);
  k_cvt<<<8, 256, 0, stream>>>(Wout, woutX, 2048);
  k_bias<<<2, 1024, 0, stream>>>(bihf, bhhf, bihb, bhhb, biasX);
  k_wmax<<<64, 256, 0, stream>>>(Whhf, Whhb, wmaxb);
  k_wquant<<<512, 256, 0, stream>>>(Whhf, Whhb, (const float*)wmaxb, whhQ);
  k_xproj<<<4096, 256, 0, stream>>>(seqs, embT, wihX, biasX, xproj);
  k_lstm<<<8, 256, 0, stream>>>(xproj, whhQ, (const float*)wmaxb, masks, h_all);
  k_emis<<<128, 256, 0, stream>>>(h_all, woutX, bout, emis);
  k_crf<<<64, 64, 0, stream>>>(emis, tags, masks, strn, etrn, trn, outf);
}

// Round 4
// 1610.600 us; speedup vs baseline: 2.5151x; 1.9446x over previous
//
#include <hip/hip_runtime.h>
#include <hip/hip_bf16.h>
#include <stdint.h>

#define DEVINL __device__ __forceinline__

typedef __attribute__((ext_vector_type(8))) short short8;
typedef __attribute__((ext_vector_type(4))) float float4v;
typedef __attribute__((ext_vector_type(4))) int int4v;

// Problem constants: V=50000, T=32, E=256, HID=512, H=256, L=512, B=64
// NL = -log2(e): x_proj is stored PRE-SCALED by NL (gates i,f,o) or 2*NL (gate g)
// so the LSTM inner loop uses only native v_exp_f32 / v_rcp_f32.
#define NLC (-1.4426950408889634f)

DEVINL float bf2f(short s) {
  union { unsigned u; float f; } v; v.u = ((unsigned)(unsigned short)s) << 16; return v.f;
}
DEVINL unsigned short f2bf(float f) {
  union { float f; unsigned u; } v; v.f = f;
  unsigned r = v.u + 0x7FFFu + ((v.u >> 16) & 1u);  // RNE
  return (unsigned short)(r >> 16);
}
DEVINL unsigned cvt_pk_bf16(float lo, float hi) {
  unsigned r;
  asm("v_cvt_pk_bf16_f32 %0, %1, %2" : "=v"(r) : "v"(lo), "v"(hi));
  return r;
}
DEVINL float ex2(float x) { return __builtin_amdgcn_exp2f(x); }
DEVINL float rcp_(float x) { return __builtin_amdgcn_rcpf(x); }

// ---------------- K0: f32 -> bf16 converts ----------------
__global__ void k_cvt(const float* __restrict__ src, short* __restrict__ dst, int n8) {
  int i = blockIdx.x * blockDim.x + threadIdx.x;
  int stride = gridDim.x * blockDim.x;
  for (; i < n8; i += stride) {
    const float4v* s = (const float4v*)(src + (size_t)i * 8);
    float4v a = s[0], b = s[1];
    short8 o;
    o[0] = (short)f2bf(a[0]); o[1] = (short)f2bf(a[1]);
    o[2] = (short)f2bf(a[2]); o[3] = (short)f2bf(a[3]);
    o[4] = (short)f2bf(b[0]); o[5] = (short)f2bf(b[1]);
    o[6] = (short)f2bf(b[2]); o[7] = (short)f2bf(b[3]);
    ((short8*)dst)[i] = o;
  }
}

__global__ void k_bias(const float* __restrict__ a1, const float* __restrict__ a2,
                       const float* __restrict__ b1, const float* __restrict__ b2,
                       float* __restrict__ o) {
  int i = blockIdx.x * blockDim.x + threadIdx.x;  // 0..2047
  o[i] = (i < 1024) ? (a1[i] + a2[i]) : (b1[i - 1024] + b2[i - 1024]);
}

// ---------------- K-wmax: per-direction max|W_hh| ----------------
__global__ void k_wmax(const float* __restrict__ Wf, const float* __restrict__ Wb,
                       unsigned* __restrict__ wmax) {
  int i = blockIdx.x * blockDim.x + threadIdx.x;
  int stride = gridDim.x * blockDim.x;
  unsigned mf = 0, mb = 0;
  for (int k = i; k < 262144; k += stride) {
    mf = max(mf, __float_as_uint(fabsf(Wf[k])));
    mb = max(mb, __float_as_uint(fabsf(Wb[k])));
  }
#pragma unroll
  for (int o = 32; o > 0; o >>= 1) {
    mf = max(mf, (unsigned)__shfl_down((int)mf, o));
    mb = max(mb, (unsigned)__shfl_down((int)mb, o));
  }
  if ((threadIdx.x & 63) == 0) { atomicMax(wmax + 0, mf); atomicMax(wmax + 1, mb); }
}

// ---------------- K-wquant: W_hh f32 -> int8 MFMA fragments ----------------
// Layout: whhQ[dir*262144 + g*65536 + w4*16384 + m4*4096 + kt*1024 + lane*16 + j]
//   unit = w4*64 + m4*16 + (lane&15); k = kt*64 + (lane>>4)*16 + j   (verified R3)
__global__ void k_wquant(const float* __restrict__ Wf, const float* __restrict__ Wb,
                         const float* __restrict__ wmax, char* __restrict__ whhQ) {
  int idx = blockIdx.x * blockDim.x + threadIdx.x;  // 0..131071 (quad of k)
  int dir = idx >> 16;
  int rem = idx & 65535;
  int r = rem >> 6;          // 0..1023 = g*256+unit
  int k = (rem & 63) * 4;
  const float* W = dir ? Wb : Wf;
  float s = 127.0f / fmaxf(wmax[dir], 1e-20f);
  int g = r >> 8, unit = r & 255;
  int w = unit >> 6, m = (unit >> 4) & 3, row = unit & 15;
  int kt = k >> 6, l4 = (k >> 4) & 3, j = k & 15;
  int lane = l4 * 16 + row;
  unsigned out = 0;
#pragma unroll
  for (int t = 0; t < 4; ++t) {
    float v = W[(size_t)r * 256 + k + t] * s;
    int q = (int)rintf(v);
    q = q < -127 ? -127 : (q > 127 ? 127 : q);
    out |= ((unsigned)(q & 255)) << (8 * t);
  }
  *(unsigned*)(whhQ + (size_t)dir * 262144 + g * 65536 + w * 16384 + m * 4096 + kt * 1024 + lane * 16 + j) = out;
}

// ---------------- K1: x_proj = (gather(emb)·W_ihᵀ + bias) * gate_scale, bf16 ----------------
__launch_bounds__(256)
__global__ void k_xproj(const int* __restrict__ seqs, const short* __restrict__ embT,
                        const short* __restrict__ wihX, const float* __restrict__ biasX,
                        short* __restrict__ xproj) {
  __shared__ short As[128 * 256];
  __shared__ short Bs[128 * 256];
  __shared__ int ids[128];
  const int bm = blockIdx.x >> 4, bn = blockIdx.x & 15;
  const int tid = threadIdx.x;
  if (tid < 128) ids[tid] = seqs[bm * 128 + tid];
  __syncthreads();
#pragma unroll
  for (int i = 0; i < 16; ++i) {
    int task = tid + i * 256, row = task >> 5, kc = task & 31;
    short8 v = *(const short8*)(embT + (size_t)ids[row] * 256 + kc * 8);
    *(short8*)((char*)As + row * 512 + ((kc * 16) ^ ((row & 7) << 4))) = v;
  }
#pragma unroll
  for (int i = 0; i < 16; ++i) {
    int task = tid + i * 256, row = task >> 5, kc = task & 31;
    short8 v = *(const short8*)(wihX + (size_t)(bn * 128 + row) * 256 + kc * 8);
    *(short8*)((char*)Bs + row * 512 + ((kc * 16) ^ ((row & 7) << 4))) = v;
  }
  __syncthreads();
  const int wave = tid >> 6, lane = tid & 63, l15 = lane & 15, l4 = lane >> 4;
  float4v acc[2][8];
#pragma unroll
  for (int m = 0; m < 2; ++m)
#pragma unroll
    for (int n = 0; n < 8; ++n) acc[m][n] = (float4v){0.f, 0.f, 0.f, 0.f};
#pragma unroll
  for (int kt = 0; kt < 8; ++kt) {
    const int kb = kt * 64 + l4 * 16;
    short8 a[2], b[8];
#pragma unroll
    for (int m = 0; m < 2; ++m) {
      int row = (wave * 2 + m) * 16 + l15;
      a[m] = *(short8*)((char*)As + row * 512 + (kb ^ ((row & 7) << 4)));
    }
#pragma unroll
    for (int n = 0; n < 8; ++n) {
      int row = n * 16 + l15;
      b[n] = *(short8*)((char*)Bs + row * 512 + (kb ^ ((row & 7) << 4)));
    }
#pragma unroll
    for (int m = 0; m < 2; ++m)
#pragma unroll
      for (int n = 0; n < 8; ++n)
        acc[m][n] = __builtin_amdgcn_mfma_f32_16x16x32_bf16(a[m], b[n], acc[m][n], 0, 0, 0);
  }
#pragma unroll
  for (int n = 0; n < 8; ++n) {
    int col = bn * 128 + n * 16 + l15;
    float bias = biasX[col];
    float scale = (((col >> 8) & 3) == 2) ? (2.f * NLC) : NLC;  // g-gate vs i,f,o
#pragma unroll
    for (int m = 0; m < 2; ++m) {
      int token = bm * 128 + (wave * 2 + m) * 16 + l4 * 4;
#pragma unroll
      for (int q = 0; q < 4; ++q)
        xproj[(size_t)(token + q) * 2048 + col] = (short)f2bf((acc[m][n][q] + bias) * scale);
    }
  }
}

// ---------------- K2: bidirectional LSTM recurrence, fully WG-local ----------------
// 8 WGs = dir (bid&1) x batch-quarter (bid>>1). 512 threads = 8 waves (2/SIMD).
// Wave w owns units [w*32, w*32+32): int8 W_hh fragments = 128 VGPRs/lane, resident.
// h int8 in double-buffered LDS (XOR-swizzled), ONE lgkm-only barrier per step.
__launch_bounds__(512, 2)
__global__ void k_lstm(const short* __restrict__ xproj, const char* __restrict__ whhQ,
                       const float* __restrict__ wmax, const int* __restrict__ masks,
                       short* __restrict__ h_all) {
  __shared__ char lds_h[2][16 * 256];
  const int bid = blockIdx.x;
  const int dir = bid & 1, bq = bid >> 1;
  const int tid = threadIdx.x, w = tid >> 6, lane = tid & 63;
  const int beta = lane & 15, l4 = lane >> 4;
  const int bglob = bq * 16 + beta;
  const float wm = wmax[dir] * (1.0f / 16129.0f);
  const float facS = wm * NLC;        // i,f,o gates
  const float facG = wm * 2.f * NLC;  // g gate

  // stationary int8 W_hh fragments [gate][m(2)][kt(4)] = 32 int4v = 128 VGPRs
  int4v wf[4][2][4];
  {
    const char* base = whhQ + (size_t)dir * 262144 + lane * 16;
#pragma unroll
    for (int g = 0; g < 4; ++g)
#pragma unroll
      for (int m = 0; m < 2; ++m) {
        int t = w * 2 + m;  // unit-tile 0..15
#pragma unroll
        for (int kt = 0; kt < 4; ++kt)
          wf[g][m][kt] = *(const int4v*)(base + g * 65536 + (t >> 2) * 16384 + (t & 3) * 4096 + kt * 1024);
      }
  }

  int rd_off[4], wr_off[2];
#pragma unroll
  for (int kt = 0; kt < 4; ++kt)
    rd_off[kt] = beta * 256 + ((kt * 64 + l4 * 16) ^ ((beta & 7) << 4));
#pragma unroll
  for (int m = 0; m < 2; ++m)
    wr_off[m] = beta * 256 + ((w * 32 + m * 16 + l4 * 4) ^ ((beta & 7) << 4));

  // h(-1) = 0 in buffer 0
  if (tid < 256) ((int4v*)lds_h[0])[tid] = (int4v){0, 0, 0, 0};

  float c[2][4], hq[2][4];
#pragma unroll
  for (int m = 0; m < 2; ++m)
#pragma unroll
    for (int q = 0; q < 4; ++q) { c[m][q] = 0.f; hq[m][q] = 0.f; }

  const short* xb = xproj + dir * 1024 + w * 32 + l4 * 4;
  union XPU { unsigned long long u; short s[4]; };
  XPU xp[4][2], xpn[4][2];
  {
    int t0 = dir ? 511 : 0;
#pragma unroll
    for (int g = 0; g < 4; ++g)
#pragma unroll
      for (int m = 0; m < 2; ++m)
        xp[g][m].u = *(const unsigned long long*)(xb + (size_t)(t0 * 64 + bglob) * 2048 + g * 256 + m * 16);
  }
  int mcur = masks[(dir ? 511 : 0) * 64 + bglob];

  auto SUBSTEP = [&](int step, const char* rb, char* wb) {
    const int tseq = dir ? (511 - step) : step;
    // barrier: prev sub-step's LDS writes visible; then read h(t-1)
    asm volatile("s_waitcnt lgkmcnt(0)" ::: "memory");
    __builtin_amdgcn_sched_barrier(0);
    __builtin_amdgcn_s_barrier();
    __builtin_amdgcn_sched_barrier(0);
    int4v bfr[4];
#pragma unroll
    for (int kt = 0; kt < 4; ++kt) bfr[kt] = *(const int4v*)(rb + rd_off[kt]);

    // prefetch next step's x_proj + mask (latency hidden under this step)
    int ns = step + 1 < 512 ? step + 1 : 511;
    int tn = dir ? (511 - ns) : ns;
    const short* xa = xb + (size_t)(tn * 64 + bglob) * 2048;
#pragma unroll
    for (int g = 0; g < 4; ++g)
#pragma unroll
      for (int m = 0; m < 2; ++m)
        xpn[g][m].u = *(const unsigned long long*)(xa + g * 256 + m * 16);
    int mn = masks[tn * 64 + bglob];

    // recurrent GEMM (int8, K=64): 32 MFMAs
    int4v iacc[4][2];
#pragma unroll
    for (int g = 0; g < 4; ++g)
#pragma unroll
      for (int m = 0; m < 2; ++m) {
        int4v t = __builtin_amdgcn_mfma_i32_16x16x64_i8(wf[g][m][0], bfr[0], (int4v){0, 0, 0, 0}, 0, 0, 0);
        t = __builtin_amdgcn_mfma_i32_16x16x64_i8(wf[g][m][1], bfr[1], t, 0, 0, 0);
        t = __builtin_amdgcn_mfma_i32_16x16x64_i8(wf[g][m][2], bfr[2], t, 0, 0, 0);
        iacc[g][m] = __builtin_amdgcn_mfma_i32_16x16x64_i8(wf[g][m][3], bfr[3], t, 0, 0, 0);
      }

    size_t hoff = (size_t)(tseq * 64 + bglob) * 512 + dir * 256 + w * 32 + l4 * 4;
#pragma unroll
    for (int m = 0; m < 2; ++m) {
      int qi[4];
      float ov_[4];
#pragma unroll
      for (int q = 0; q < 4; ++q) {
        float ai = fmaf((float)iacc[0][m][q], facS, bf2f(xp[0][m].s[q]));
        float af = fmaf((float)iacc[1][m][q], facS, bf2f(xp[1][m].s[q]));
        float ag = fmaf((float)iacc[2][m][q], facG, bf2f(xp[2][m].s[q]));
        float ao = fmaf((float)iacc[3][m][q], facS, bf2f(xp[3][m].s[q]));
        float iv = rcp_(1.f + ex2(ai));
        float fv = rcp_(1.f + ex2(af));
        float gv = fmaf(2.f, rcp_(1.f + ex2(ag)), -1.f);
        float ovv = rcp_(1.f + ex2(ao));
        float cn = fmaf(fv, c[m][q], iv * gv);
        float tc = fmaf(2.f, rcp_(1.f + ex2(cn * (2.f * NLC))), -1.f);
        float hn = ovv * tc;
        c[m][q] = mcur ? cn : c[m][q];
        float hv = mcur ? hn : hq[m][q];
        hq[m][q] = hv;
        ov_[q] = mcur ? hn : 0.f;
        qi[q] = (int)rintf(hv * 127.f);
      }
      unsigned p0 = __builtin_amdgcn_perm((unsigned)qi[1], (unsigned)qi[0], 0x0c0c0400u);
      unsigned p1 = __builtin_amdgcn_perm((unsigned)qi[3], (unsigned)qi[2], 0x0c0c0400u);
      unsigned qpack = __builtin_amdgcn_perm(p1, p0, 0x05040100u);
      *(unsigned*)(wb + wr_off[m]) = qpack;  // publish h int8 to LDS (other buffer)
      uint2 ob;
      ob.x = cvt_pk_bf16(ov_[0], ov_[1]);
      ob.y = cvt_pk_bf16(ov_[2], ov_[3]);
      *(uint2*)(h_all + hoff + m * 16) = ob;  // bf16 output, off critical path
    }
#pragma unroll
    for (int g = 0; g < 4; ++g)
#pragma unroll
      for (int m = 0; m < 2; ++m) xp[g][m] = xpn[g][m];
    mcur = mn;
  };

#pragma unroll 1
  for (int s2 = 0; s2 < 256; ++s2) {
    SUBSTEP(2 * s2,     lds_h[0], lds_h[1]);
    SUBSTEP(2 * s2 + 1, lds_h[1], lds_h[0]);
  }
}

// ---------------- K3: emissions = h_all·W_outᵀ + b_out (f32) ----------------
__launch_bounds__(256)
__global__ void k_emis(const short* __restrict__ h_all, const short* __restrict__ woutX,
                       const float* __restrict__ bout, float* __restrict__ emis) {
  const int tid = threadIdx.x, wave = tid >> 6, lane = tid & 63;
  const int l15 = lane & 15, l4 = lane >> 4;
  const int token0 = blockIdx.x * 256 + wave * 64;
  float4v acc[4][2];
#pragma unroll
  for (int m = 0; m < 4; ++m)
#pragma unroll
    for (int n = 0; n < 2; ++n) acc[m][n] = (float4v){0.f, 0.f, 0.f, 0.f};
#pragma unroll
  for (int kt = 0; kt < 16; ++kt) {
    short8 b[2];
#pragma unroll
    for (int n = 0; n < 2; ++n)
      b[n] = *(const short8*)(woutX + (size_t)(n * 16 + l15) * 512 + kt * 32 + l4 * 8);
#pragma unroll
    for (int m = 0; m < 4; ++m) {
      short8 a = *(const short8*)(h_all + (size_t)(token0 + m * 16 + l15) * 512 + kt * 32 + l4 * 8);
#pragma unroll
      for (int n = 0; n < 2; ++n)
        acc[m][n] = __builtin_amdgcn_mfma_f32_16x16x32_bf16(a, b[n], acc[m][n], 0, 0, 0);
    }
  }
#pragma unroll
  for (int n = 0; n < 2; ++n) {
    float bias = bout[n * 16 + l15];
#pragma unroll
    for (int m = 0; m < 4; ++m) {
      int token = token0 + m * 16 + l4 * 4;
#pragma unroll
      for (int q = 0; q < 4; ++q)
        emis[(size_t)(token + q) * 32 + n * 16 + l15] = acc[m][n][q] + bias;
    }
  }
}

// ---------------- K4: CRF numerator + partition scan + final reduce ----------------
__launch_bounds__(64)
__global__ void k_crf(const float* __restrict__ emis, const int* __restrict__ tags,
                      const int* __restrict__ masks, const float* __restrict__ strans,
                      const float* __restrict__ etrans, const float* __restrict__ trans,
                      float* __restrict__ out) {
  __shared__ float trans_s[1024];
  __shared__ float score_s[32];
  const float L2E = 1.4426950408889634f;
  const int b = blockIdx.x, lane = threadIdx.x;
  for (int i = lane; i < 1024; i += 64) trans_s[i] = trans[i];

  float num = 0.f; int lensum = 0;
#pragma unroll 1
  for (int i = 0; i < 8; ++i) {
    int t = lane + i * 64;
    int tg = tags[t * 64 + b];
    int m = masks[t * 64 + b];
    lensum += m;
    float e = emis[(size_t)(t * 64 + b) * 32 + tg];
    if (t == 0) num += strans[tg] + e;
    else if (m) num += e + trans[tags[(t - 1) * 64 + b] * 32 + tg];
  }
#pragma unroll
  for (int o = 32; o > 0; o >>= 1) { num += __shfl_down(num, o); lensum += __shfl_down(lensum, o); }
  num = __shfl(num, 0);
  lensum = __shfl(lensum, 0);
  num += etrans[tags[(lensum - 1) * 64 + b]];
  __syncthreads();

  const int jp = lane & 31, half = lane >> 5;
  if (lane < 32) score_s[jp] = strans[jp] + emis[(size_t)b * 32 + jp];
  __syncthreads();

  float e_next = emis[(size_t)(64 + b) * 32 + jp];
#pragma unroll 1
  for (int t = 1; t < 512; ++t) {
    float e = e_next;
    if (t < 511) e_next = emis[(size_t)((t + 1) * 64 + b) * 32 + jp];
    int m = masks[t * 64 + b];
    float v[16], mx = -1e30f;
#pragma unroll
    for (int j = 0; j < 16; ++j) {
      v[j] = score_s[half * 16 + j] + trans_s[(half * 16 + j) * 32 + jp];
      mx = fmaxf(mx, v[j]);
    }
    float sum = 0.f;
#pragma unroll
    for (int j = 0; j < 16; ++j) sum += ex2((v[j] - mx) * L2E);
    float mo = __shfl_xor(mx, 32), so = __shfl_xor(sum, 32);
    float mn2 = fmaxf(mx, mo);
    sum = sum * ex2((mx - mn2) * L2E) + so * ex2((mo - mn2) * L2E);
    float nxt = e + mn2 + __builtin_amdgcn_logf(sum) * (1.f / L2E);
    float cur = score_s[jp];
    float ns = m ? nxt : cur;
    __syncthreads();
    if (lane < 32) score_s[jp] = ns;
    __syncthreads();
  }

  float vv = (lane < 32) ? (score_s[jp] + etrans[jp]) : -1e30f;
  float mx = vv;
#pragma unroll
  for (int o = 32; o > 0; o >>= 1) mx = fmaxf(mx, __shfl_xor(mx, o));
  float sm = (lane < 32) ? ex2((vv - mx) * L2E) : 0.f;
#pragma unroll
  for (int o = 32; o > 0; o >>= 1) sm += __shfl_xor(sm, o);
  float lz = mx + __builtin_amdgcn_logf(sm) * (1.f / L2E);
  if (lane == 0) atomicAdd(out, -(num - lz) * (1.0f / 64.0f));
}

// ---------------- launch ----------------
extern "C" void kernel_launch(void* const* d_in, const int* in_sizes, int n_in,
                              void* d_out, int out_size, void* d_ws, size_t ws_size,
                              hipStream_t stream) {
  const int*   seqs  = (const int*)d_in[0];
  const int*   tags  = (const int*)d_in[1];
  const int*   masks = (const int*)d_in[2];
  const float* embed = (const float*)d_in[3];
  const float* Wihf  = (const float*)d_in[4];
  const float* Whhf  = (const float*)d_in[5];
  const float* bihf  = (const float*)d_in[6];
  const float* bhhf  = (const float*)d_in[7];
  const float* Wihb  = (const float*)d_in[8];
  const float* Whhb  = (const float*)d_in[9];
  const float* bihb  = (const float*)d_in[10];
  const float* bhhb  = (const float*)d_in[11];
  const float* Wout  = (const float*)d_in[12];
  const float* bout  = (const float*)d_in[13];
  const float* strn  = (const float*)d_in[14];
  const float* etrn  = (const float*)d_in[15];
  const float* trn   = (const float*)d_in[16];
  float* outf = (float*)d_out;

  char* ws = (char*)d_ws;
  short* xproj = (short*)(ws + 0);             // 134,217,728 B
  short* h_all = (short*)(ws + 134217728);     //  33,554,432 B
  float* emis  = (float*)(ws + 167772160);     //   4,194,304 B
  short* embT  = (short*)(ws + 171966464);     //  25,600,000 B
  short* wihX  = (short*)(ws + 197566464);     //   1,048,576 B
  char*  whhQ  = (char*)(ws + 198615040);      //     524,288 B (int8 fragments)
  unsigned* wmaxb = (unsigned*)(ws + 199139328); //         8 B
  short* woutX = (short*)(ws + 199663616);     //      32,768 B
  float* biasX = (float*)(ws + 199696384);     //       8,192 B

  hipMemsetAsync(d_out, 0, 4, stream);
  hipMemsetAsync(wmaxb, 0, 8, stream);

  k_cvt<<<2048, 256, 0, stream>>>(embed, embT, 1600000);
  k_cvt<<<128, 256, 0, stream>>>(Wihf, wihX, 32768);
  k_cvt<<<128, 256, 0, stream>>>(Wihb, wihX + 262144, 32768);
  k_cvt<<<8, 256, 0, stream>>>(Wout, woutX, 2048);
  k_bias<<<2, 1024, 0, stream>>>(bihf, bhhf, bihb, bhhb, biasX);
  k_wmax<<<64, 256, 0, stream>>>(Whhf, Whhb, wmaxb);
  k_wquant<<<512, 256, 0, stream>>>(Whhf, Whhb, (const float*)wmaxb, whhQ);
  k_xproj<<<4096, 256, 0, stream>>>(seqs, embT, wihX, biasX, xproj);
  k_lstm<<<8, 512, 0, stream>>>(xproj, whhQ, (const float*)wmaxb, masks, h_all);
  k_emis<<<128, 256, 0, stream>>>(h_all, woutX, bout, emis);
  k_crf<<<64, 64, 0, stream>>>(emis, tags, masks, strn, etrn, trn, outf);
}

// Round 5
// 1589.539 us; speedup vs baseline: 2.5485x; 1.0132x over previous
//
#include <hip/hip_runtime.h>
#include <hip/hip_bf16.h>
#include <stdint.h>

#define DEVINL __device__ __forceinline__

typedef __attribute__((ext_vector_type(8))) short short8;
typedef __attribute__((ext_vector_type(4))) float float4v;
typedef __attribute__((ext_vector_type(4))) int int4v;

// Problem constants: V=50000, T=32, E=256, HID=512, H=256, L=512, B=64
// xproj stores preact * NL (i,f,o) or * 2NL (g), NL = -log2(e), so the LSTM
// inner loop needs only native v_exp_f32 / v_rcp_f32.
#define NLC (-1.4426950408889634f)

DEVINL float uif(unsigned u) { union { unsigned u; float f; } v; v.u = u; return v.f; }
DEVINL float bf2f(short s) { return uif(((unsigned)(unsigned short)s) << 16); }
DEVINL unsigned short f2bf(float f) {
  union { float f; unsigned u; } v; v.f = f;
  unsigned r = v.u + 0x7FFFu + ((v.u >> 16) & 1u);  // RNE
  return (unsigned short)(r >> 16);
}
DEVINL unsigned cvt_pk_bf16(float lo, float hi) {
  unsigned r;
  asm("v_cvt_pk_bf16_f32 %0, %1, %2" : "=v"(r) : "v"(lo), "v"(hi));
  return r;
}
DEVINL float ex2(float x) { return __builtin_amdgcn_exp2f(x); }
DEVINL float rcp_(float x) { return __builtin_amdgcn_rcpf(x); }
// unpack 4 bf16 from a packed 64-bit word (1 inst per value)
DEVINL void unp4(unsigned long long u, float* f) {
  unsigned lo = (unsigned)u, hi = (unsigned)(u >> 32);
  f[0] = uif(lo << 16); f[1] = uif(lo & 0xffff0000u);
  f[2] = uif(hi << 16); f[3] = uif(hi & 0xffff0000u);
}

#define LBAR() do { \
  asm volatile("s_waitcnt lgkmcnt(0)" ::: "memory"); \
  __builtin_amdgcn_sched_barrier(0); \
  __builtin_amdgcn_s_barrier(); \
  __builtin_amdgcn_sched_barrier(0); \
} while (0)

// ---------------- K0: f32 -> bf16 converts ----------------
__global__ void k_cvt(const float* __restrict__ src, short* __restrict__ dst, int n8) {
  int i = blockIdx.x * blockDim.x + threadIdx.x;
  int stride = gridDim.x * blockDim.x;
  for (; i < n8; i += stride) {
    const float4v* s = (const float4v*)(src + (size_t)i * 8);
    float4v a = s[0], b = s[1];
    short8 o;
    o[0] = (short)f2bf(a[0]); o[1] = (short)f2bf(a[1]);
    o[2] = (short)f2bf(a[2]); o[3] = (short)f2bf(a[3]);
    o[4] = (short)f2bf(b[0]); o[5] = (short)f2bf(b[1]);
    o[6] = (short)f2bf(b[2]); o[7] = (short)f2bf(b[3]);
    ((short8*)dst)[i] = o;
  }
}

__global__ void k_bias(const float* __restrict__ a1, const float* __restrict__ a2,
                       const float* __restrict__ b1, const float* __restrict__ b2,
                       float* __restrict__ o) {
  int i = blockIdx.x * blockDim.x + threadIdx.x;  // 0..2047
  o[i] = (i < 1024) ? (a1[i] + a2[i]) : (b1[i - 1024] + b2[i - 1024]);
}

// ---------------- K-wmax: per-direction max|W_hh| ----------------
__global__ void k_wmax(const float* __restrict__ Wf, const float* __restrict__ Wb,
                       unsigned* __restrict__ wmax) {
  int i = blockIdx.x * blockDim.x + threadIdx.x;
  int stride = gridDim.x * blockDim.x;
  unsigned mf = 0, mb = 0;
  for (int k = i; k < 262144; k += stride) {
    mf = max(mf, __float_as_uint(fabsf(Wf[k])));
    mb = max(mb, __float_as_uint(fabsf(Wb[k])));
  }
#pragma unroll
  for (int o = 32; o > 0; o >>= 1) {
    mf = max(mf, (unsigned)__shfl_down((int)mf, o));
    mb = max(mb, (unsigned)__shfl_down((int)mb, o));
  }
  if ((threadIdx.x & 63) == 0) { atomicMax(wmax + 0, mf); atomicMax(wmax + 1, mb); }
}

// ---------------- K-wquant: W_hh f32 -> int8 MFMA fragments (layout verified R3) ------
__global__ void k_wquant(const float* __restrict__ Wf, const float* __restrict__ Wb,
                         const float* __restrict__ wmax, char* __restrict__ whhQ) {
  int idx = blockIdx.x * blockDim.x + threadIdx.x;  // 0..131071 (quad of k)
  int dir = idx >> 16;
  int rem = idx & 65535;
  int r = rem >> 6;          // 0..1023 = g*256+unit
  int k = (rem & 63) * 4;
  const float* W = dir ? Wb : Wf;
  float s = 127.0f / fmaxf(wmax[dir], 1e-20f);
  int g = r >> 8, unit = r & 255;
  int w = unit >> 6, m = (unit >> 4) & 3, row = unit & 15;
  int kt = k >> 6, l4 = (k >> 4) & 3, j = k & 15;
  int lane = l4 * 16 + row;
  unsigned out = 0;
#pragma unroll
  for (int t = 0; t < 4; ++t) {
    float v = W[(size_t)r * 256 + k + t] * s;
    int q = (int)rintf(v);
    q = q < -127 ? -127 : (q > 127 ? 127 : q);
    out |= ((unsigned)(q & 255)) << (8 * t);
  }
  *(unsigned*)(whhQ + (size_t)dir * 262144 + g * 65536 + w * 16384 + m * 4096 + kt * 1024 + lane * 16 + j) = out;
}

// ---------------- K1: x_proj, A staged once per WG, 16 B-tiles looped ----------------
__launch_bounds__(256)
__global__ void k_xproj(const int* __restrict__ seqs, const short* __restrict__ embT,
                        const short* __restrict__ wihX, const float* __restrict__ biasX,
                        short* __restrict__ xproj) {
  __shared__ short As[128 * 256];
  __shared__ short Bs[128 * 256];
  __shared__ int ids[128];
  const int bm = blockIdx.x;
  const int tid = threadIdx.x;
  if (tid < 128) ids[tid] = seqs[bm * 128 + tid];
  __syncthreads();
#pragma unroll
  for (int i = 0; i < 16; ++i) {  // stage A (gathered embeddings) ONCE
    int task = tid + i * 256, row = task >> 5, kc = task & 31;
    short8 v = *(const short8*)(embT + (size_t)ids[row] * 256 + kc * 8);
    *(short8*)((char*)As + row * 512 + ((kc * 16) ^ ((row & 7) << 4))) = v;
  }
  __syncthreads();
  const int wave = tid >> 6, lane = tid & 63, l15 = lane & 15, l4 = lane >> 4;
  // hoist A fragments to registers (64 VGPR)
  short8 af[2][8];
#pragma unroll
  for (int m = 0; m < 2; ++m) {
    int row = (wave * 2 + m) * 16 + l15;
#pragma unroll
    for (int kt = 0; kt < 8; ++kt)
      af[m][kt] = *(short8*)((char*)As + row * 512 + ((kt * 64 + l4 * 16) ^ ((row & 7) << 4)));
  }
#pragma unroll 1
  for (int bn = 0; bn < 16; ++bn) {
    __syncthreads();  // previous compute done reading Bs
#pragma unroll
    for (int i = 0; i < 16; ++i) {
      int task = tid + i * 256, row = task >> 5, kc = task & 31;
      short8 v = *(const short8*)(wihX + (size_t)(bn * 128 + row) * 256 + kc * 8);
      *(short8*)((char*)Bs + row * 512 + ((kc * 16) ^ ((row & 7) << 4))) = v;
    }
    __syncthreads();
    float4v acc[2][8];
#pragma unroll
    for (int m = 0; m < 2; ++m)
#pragma unroll
      for (int n = 0; n < 8; ++n) acc[m][n] = (float4v){0.f, 0.f, 0.f, 0.f};
#pragma unroll
    for (int kt = 0; kt < 8; ++kt) {
      const int kb = kt * 64 + l4 * 16;
      short8 b[8];
#pragma unroll
      for (int n = 0; n < 8; ++n) {
        int row = n * 16 + l15;
        b[n] = *(short8*)((char*)Bs + row * 512 + (kb ^ ((row & 7) << 4)));
      }
#pragma unroll
      for (int m = 0; m < 2; ++m)
#pragma unroll
        for (int n = 0; n < 8; ++n)
          acc[m][n] = __builtin_amdgcn_mfma_f32_16x16x32_bf16(af[m][kt], b[n], acc[m][n], 0, 0, 0);
    }
#pragma unroll
    for (int n = 0; n < 8; ++n) {
      int col = bn * 128 + n * 16 + l15;
      float bias = biasX[col];
      float scale = (((col >> 8) & 3) == 2) ? (2.f * NLC) : NLC;  // g-gate vs i,f,o
#pragma unroll
      for (int m = 0; m < 2; ++m) {
        int token = bm * 128 + (wave * 2 + m) * 16 + l4 * 4;
#pragma unroll
        for (int q = 0; q < 4; ++q)
          xproj[(size_t)(token + q) * 2048 + col] = (short)f2bf((acc[m][n][q] + bias) * scale);
      }
    }
  }
}

// ---------------- K2: bidirectional LSTM recurrence, fully WG-local ----------------
// 8 WGs = dir x batch-quarter. 512 threads = 8 waves (2/SIMD). Wave w owns units
// [w*32,w*32+32); int8 W_hh fragments resident (AGPR file). h int8 double-buffered in
// LDS, one lgkm-only barrier/substep. Pointer-bump addressing + register ping-pong.
__launch_bounds__(512, 2)
__global__ void k_lstm(const short* __restrict__ xproj, const char* __restrict__ whhQ,
                       const float* __restrict__ wmax, const int* __restrict__ mask_ws,
                       short* __restrict__ h_all) {
  __shared__ char lds_h[2][16 * 256];
  const int bid = blockIdx.x;
  const int dir = bid & 1, bq = bid >> 1;
  const int tid = threadIdx.x, w = tid >> 6, lane = tid & 63;
  const int beta = lane & 15, l4 = lane >> 4;
  const int bglob = bq * 16 + beta;
  const float wm = wmax[dir] * (1.0f / 16129.0f);
  const float facS = wm * NLC;
  const float facG = wm * 2.f * NLC;

  // stationary int8 W_hh fragments
  int4v wf[4][2][4];
  {
    const char* base = whhQ + (size_t)dir * 262144 + lane * 16;
#pragma unroll
    for (int g = 0; g < 4; ++g)
#pragma unroll
      for (int m = 0; m < 2; ++m) {
        int t = w * 2 + m;
#pragma unroll
        for (int kt = 0; kt < 4; ++kt)
          wf[g][m][kt] = *(const int4v*)(base + g * 65536 + (t >> 2) * 16384 + (t & 3) * 4096 + kt * 1024);
      }
  }

  int rd_off[4], wr_off[2];
#pragma unroll
  for (int kt = 0; kt < 4; ++kt)
    rd_off[kt] = beta * 256 + ((kt * 64 + l4 * 16) ^ ((beta & 7) << 4));
#pragma unroll
  for (int m = 0; m < 2; ++m)
    wr_off[m] = beta * 256 + ((w * 32 + m * 16 + l4 * 4) ^ ((beta & 7) << 4));

  if (tid < 256) ((int4v*)lds_h[0])[tid] = (int4v){0, 0, 0, 0};

  float c[2][4], hq[2][4];
#pragma unroll
  for (int m = 0; m < 2; ++m)
#pragma unroll
    for (int q = 0; q < 4; ++q) { c[m][q] = 0.f; hq[m][q] = 0.f; }

  // carried pointers, bumped by wave-uniform strides (prefetch may run one step
  // past either end: xproj/mask_ws have guard regions in the workspace)
  const int t0 = dir ? 511 : 0;
  const int SD = dir ? -131072 : 131072;   // xproj shorts per step
  const int SM = dir ? -64 : 64;           // mask ints per step
  const int SH = dir ? -32768 : 32768;     // h_all shorts per step
  const short* px = xproj + (size_t)(t0 * 64 + bglob) * 2048 + dir * 1024 + w * 32 + l4 * 4;
  const int* pm = mask_ws + t0 * 64 + bglob;
  short* ph = h_all + (size_t)(t0 * 64 + bglob) * 512 + dir * 256 + w * 32 + l4 * 4;

  unsigned long long X0[4][2], X1[4][2];
  int m0, m1;
#pragma unroll
  for (int g = 0; g < 4; ++g)
#pragma unroll
    for (int m = 0; m < 2; ++m)
      X0[g][m] = *(const unsigned long long*)(px + g * 256 + m * 16);
  m0 = *pm;
  px += SD; pm += SM;

  auto SUB = [&](unsigned long long (&xc)[4][2], int& mc,
                 unsigned long long (&xn)[4][2], int& mn,
                 const char* rb, char* wb) {
    LBAR();  // prev substep's LDS writes visible
    int4v bfr[4];
#pragma unroll
    for (int kt = 0; kt < 4; ++kt) bfr[kt] = *(const int4v*)(rb + rd_off[kt]);

    // prefetch next step (immediate offsets off one carried pointer)
#pragma unroll
    for (int g = 0; g < 4; ++g)
#pragma unroll
      for (int m = 0; m < 2; ++m)
        xn[g][m] = *(const unsigned long long*)(px + g * 256 + m * 16);
    mn = *pm;
    px += SD; pm += SM;

    int4v iacc[4][2];
#pragma unroll
    for (int g = 0; g < 4; ++g)
#pragma unroll
      for (int m = 0; m < 2; ++m) {
        int4v t = __builtin_amdgcn_mfma_i32_16x16x64_i8(wf[g][m][0], bfr[0], (int4v){0, 0, 0, 0}, 0, 0, 0);
        t = __builtin_amdgcn_mfma_i32_16x16x64_i8(wf[g][m][1], bfr[1], t, 0, 0, 0);
        t = __builtin_amdgcn_mfma_i32_16x16x64_i8(wf[g][m][2], bfr[2], t, 0, 0, 0);
        iacc[g][m] = __builtin_amdgcn_mfma_i32_16x16x64_i8(wf[g][m][3], bfr[3], t, 0, 0, 0);
      }

#pragma unroll
    for (int m = 0; m < 2; ++m) {
      float xi[4], xf[4], xg[4], xo[4];
      unp4(xc[0][m], xi); unp4(xc[1][m], xf); unp4(xc[2][m], xg); unp4(xc[3][m], xo);
      unsigned qb[4]; float ov[4];
#pragma unroll
      for (int q = 0; q < 4; ++q) {
        float ai = fmaf((float)iacc[0][m][q], facS, xi[q]);
        float af_ = fmaf((float)iacc[1][m][q], facS, xf[q]);
        float ag = fmaf((float)iacc[2][m][q], facG, xg[q]);
        float ao = fmaf((float)iacc[3][m][q], facS, xo[q]);
        float Ei = fminf(ex2(ai), 1e30f);
        float Ef = fminf(ex2(af_), 1e30f);
        float Eg = fminf(ex2(ag), 1e30f);
        float Eo = fminf(ex2(ao), 1e30f);
        float ig = (1.f - Eg) * rcp_((1.f + Ei) * (1.f + Eg));   // sigmoid(i)*tanh(g)
        float fv = rcp_(1.f + Ef);
        float cn = fmaf(fv, c[m][q], ig);
        float Ec = fminf(ex2(cn * (2.f * NLC)), 1e30f);
        float hn = (1.f - Ec) * rcp_((1.f + Eo) * (1.f + Ec));   // sigmoid(o)*tanh(c)
        c[m][q] = mc ? cn : c[m][q];
        float hv = mc ? hn : hq[m][q];
        hq[m][q] = hv;
        ov[q] = mc ? hn : 0.f;
        qb[q] = __float_as_uint(fmaf(hv, 127.f, 12582912.f));  // low byte = int8(h*127)
      }
      unsigned p0 = __builtin_amdgcn_perm(qb[1], qb[0], 0x0c0c0400u);
      unsigned p1 = __builtin_amdgcn_perm(qb[3], qb[2], 0x0c0c0400u);
      unsigned qpack = __builtin_amdgcn_perm(p1, p0, 0x05040100u);
      *(unsigned*)(wb + wr_off[m]) = qpack;
      uint2 ob;
      ob.x = cvt_pk_bf16(ov[0], ov[1]);
      ob.y = cvt_pk_bf16(ov[2], ov[3]);
      *(uint2*)(ph + m * 16) = ob;
    }
    ph += SH;
  };

#pragma unroll 1
  for (int s2 = 0; s2 < 256; ++s2) {
    SUB(X0, m0, X1, m1, lds_h[0], lds_h[1]);
    SUB(X1, m1, X0, m0, lds_h[1], lds_h[0]);
  }
}

// ---------------- K3: emissions = h_all·W_outᵀ + b_out (f32) ----------------
__launch_bounds__(256)
__global__ void k_emis(const short* __restrict__ h_all, const short* __restrict__ woutX,
                       const float* __restrict__ bout, float* __restrict__ emis) {
  const int tid = threadIdx.x, wave = tid >> 6, lane = tid & 63;
  const int l15 = lane & 15, l4 = lane >> 4;
  const int token0 = blockIdx.x * 256 + wave * 64;
  float4v acc[4][2];
#pragma unroll
  for (int m = 0; m < 4; ++m)
#pragma unroll
    for (int n = 0; n < 2; ++n) acc[m][n] = (float4v){0.f, 0.f, 0.f, 0.f};
#pragma unroll
  for (int kt = 0; kt < 16; ++kt) {
    short8 b[2];
#pragma unroll
    for (int n = 0; n < 2; ++n)
      b[n] = *(const short8*)(woutX + (size_t)(n * 16 + l15) * 512 + kt * 32 + l4 * 8);
#pragma unroll
    for (int m = 0; m < 4; ++m) {
      short8 a = *(const short8*)(h_all + (size_t)(token0 + m * 16 + l15) * 512 + kt * 32 + l4 * 8);
#pragma unroll
      for (int n = 0; n < 2; ++n)
        acc[m][n] = __builtin_amdgcn_mfma_f32_16x16x32_bf16(a, b[n], acc[m][n], 0, 0, 0);
    }
  }
#pragma unroll
  for (int n = 0; n < 2; ++n) {
    float bias = bout[n * 16 + l15];
#pragma unroll
    for (int m = 0; m < 4; ++m) {
      int token = token0 + m * 16 + l4 * 4;
#pragma unroll
      for (int q = 0; q < 4; ++q)
        emis[(size_t)(token + q) * 32 + n * 16 + l15] = acc[m][n][q] + bias;
    }
  }
}

// ---------------- K4: CRF numerator + partition scan + final reduce ----------------
__launch_bounds__(64)
__global__ void k_crf(const float* __restrict__ emis, const int* __restrict__ tags,
                      const int* __restrict__ masks, const float* __restrict__ strans,
                      const float* __restrict__ etrans, const float* __restrict__ trans,
                      float* __restrict__ out) {
  __shared__ float trans_s[1024];
  __shared__ float score_s[32];
  const float L2E = 1.4426950408889634f;
  const int b = blockIdx.x, lane = threadIdx.x;
  for (int i = lane; i < 1024; i += 64) trans_s[i] = trans[i];

  float num = 0.f; int lensum = 0;
#pragma unroll 1
  for (int i = 0; i < 8; ++i) {
    int t = lane + i * 64;
    int tg = tags[t * 64 + b];
    int m = masks[t * 64 + b];
    lensum += m;
    float e = emis[(size_t)(t * 64 + b) * 32 + tg];
    if (t == 0) num += strans[tg] + e;
    else if (m) num += e + trans[tags[(t - 1) * 64 + b] * 32 + tg];
  }
#pragma unroll
  for (int o = 32; o > 0; o >>= 1) { num += __shfl_down(num, o); lensum += __shfl_down(lensum, o); }
  num = __shfl(num, 0);
  lensum = __shfl(lensum, 0);
  num += etrans[tags[(lensum - 1) * 64 + b]];
  __syncthreads();

  const int jp = lane & 31, half = lane >> 5;
  if (lane < 32) score_s[jp] = strans[jp] + emis[(size_t)b * 32 + jp];
  __syncthreads();

  float e_next = emis[(size_t)(64 + b) * 32 + jp];
#pragma unroll 1
  for (int t = 1; t < 512; ++t) {
    float e = e_next;
    if (t < 511) e_next = emis[(size_t)((t + 1) * 64 + b) * 32 + jp];
    int m = masks[t * 64 + b];
    float v[16], mx = -1e30f;
#pragma unroll
    for (int j = 0; j < 16; ++j) {
      v[j] = score_s[half * 16 + j] + trans_s[(half * 16 + j) * 32 + jp];
      mx = fmaxf(mx, v[j]);
    }
    float sum = 0.f;
#pragma unroll
    for (int j = 0; j < 16; ++j) sum += ex2((v[j] - mx) * L2E);
    float mo = __shfl_xor(mx, 32), so = __shfl_xor(sum, 32);
    float mn2 = fmaxf(mx, mo);
    sum = sum * ex2((mx - mn2) * L2E) + so * ex2((mo - mn2) * L2E);
    float nxt = e + mn2 + __builtin_amdgcn_logf(sum) * (1.f / L2E);
    float cur = score_s[jp];
    float ns = m ? nxt : cur;
    __syncthreads();
    if (lane < 32) score_s[jp] = ns;
    __syncthreads();
  }

  float vv = (lane < 32) ? (score_s[jp] + etrans[jp]) : -1e30f;
  float mx = vv;
#pragma unroll
  for (int o = 32; o > 0; o >>= 1) mx = fmaxf(mx, __shfl_xor(mx, o));
  float sm = (lane < 32) ? ex2((vv - mx) * L2E) : 0.f;
#pragma unroll
  for (int o = 32; o > 0; o >>= 1) sm += __shfl_xor(sm, o);
  float lz = mx + __builtin_amdgcn_logf(sm) * (1.f / L2E);
  if (lane == 0) atomicAdd(out, -(num - lz) * (1.0f / 64.0f));
}

// ---------------- launch ----------------
extern "C" void kernel_launch(void* const* d_in, const int* in_sizes, int n_in,
                              void* d_out, int out_size, void* d_ws, size_t ws_size,
                              hipStream_t stream) {
  const int*   seqs  = (const int*)d_in[0];
  const int*   tags  = (const int*)d_in[1];
  const int*   masks = (const int*)d_in[2];
  const float* embed = (const float*)d_in[3];
  const float* Wihf  = (const float*)d_in[4];
  const float* Whhf  = (const float*)d_in[5];
  const float* bihf  = (const float*)d_in[6];
  const float* bhhf  = (const float*)d_in[7];
  const float* Wihb  = (const float*)d_in[8];
  const float* Whhb  = (const float*)d_in[9];
  const float* bihb  = (const float*)d_in[10];
  const float* bhhb  = (const float*)d_in[11];
  const float* Wout  = (const float*)d_in[12];
  const float* bout  = (const float*)d_in[13];
  const float* strn  = (const float*)d_in[14];
  const float* etrn  = (const float*)d_in[15];
  const float* trn   = (const float*)d_in[16];
  float* outf = (float*)d_out;

  char* ws = (char*)d_ws;
  // [0, 262144): guard for k_lstm's one-step-past prefetch (dir=1)
  short* xproj = (short*)(ws + 262144);          // 134,217,728 B (dir=0 overread -> h_all, fine)
  short* h_all = (short*)(ws + 134479872);       //  33,554,432 B
  float* emis  = (float*)(ws + 168034304);       //   4,194,304 B
  short* embT  = (short*)(ws + 172228608);       //  25,600,000 B
  short* wihX  = (short*)(ws + 197828608);       //   1,048,576 B
  char*  whhQ  = (char*)(ws + 198877184);        //     524,288 B
  short* woutX = (short*)(ws + 199401472);       //      32,768 B
  float* biasX = (float*)(ws + 199434240);       //       8,192 B
  unsigned* wmaxb = (unsigned*)(ws + 199442432); //       256 B
  int* mask_ws = (int*)(ws + 199442944);         // 131,072 B (+256 B guards both sides)

  hipMemsetAsync(d_out, 0, 4, stream);
  hipMemsetAsync(wmaxb, 0, 8, stream);
  hipMemcpyAsync(mask_ws, masks, 131072, hipMemcpyDeviceToDevice, stream);

  k_cvt<<<2048, 256, 0, stream>>>(embed, embT, 1600000);
  k_cvt<<<128, 256, 0, stream>>>(Wihf, wihX, 32768);
  k_cvt<<<128, 256, 0, stream>>>(Wihb, wihX + 262144, 32768);
  k_cvt<<<8, 256, 0, stream>>>(Wout, woutX, 2048);
  k_bias<<<2, 1024, 0, stream>>>(bihf, bhhf, bihb, bhhb, biasX);
  k_wmax<<<64, 256, 0, stream>>>(Whhf, Whhb, wmaxb);
  k_wquant<<<512, 256, 0, stream>>>(Whhf, Whhb, (const float*)wmaxb, whhQ);
  k_xproj<<<256, 256, 0, stream>>>(seqs, embT, wihX, biasX, xproj);
  k_lstm<<<8, 512, 0, stream>>>(xproj, whhQ, (const float*)wmaxb, mask_ws, h_all);
  k_emis<<<128, 256, 0, stream>>>(h_all, woutX, bout, emis);
  k_crf<<<64, 64, 0, stream>>>(emis, tags, masks, strn, etrn, trn, outf);
}